// Round 28
// baseline (139.679 us; speedup 1.0000x reference)
//
#include <hip/hip_runtime.h>
#include <hip/hip_bf16.h>

#define TPB  256
#define WPB  4              // waves per block; 1 block/CU (serial regime)
#define NBLK 256
#define PROW 136            // panel row stride in shorts (272B = odd*16B)
#define PSZ  (128 * PROW)   // shorts per panel

typedef short    short8 __attribute__((ext_vector_type(8)));
typedef float    f32x4  __attribute__((ext_vector_type(4)));
typedef unsigned uint4v __attribute__((ext_vector_type(4)));

#define SBAR() __builtin_amdgcn_sched_barrier(0)

// No local arrays anywhere; named-member structs by value only.
struct Frag   { short8 k0, k1, k2, k3; };
struct Acc8   { f32x4 n0, n1, n2, n3, n4, n5, n6, n7; };
struct Acc8x6 { Acc8 a, b, c, d, e, f; };

__device__ __forceinline__ f32x4 sp4(float v) { f32x4 r = {v, v, v, v}; return r; }

__device__ __forceinline__ float fast_tanh(float z) {
    float e = __expf(2.0f * z);
    return 1.0f - 2.0f * __builtin_amdgcn_rcpf(e + 1.0f);
}
__device__ __forceinline__ f32x4 tanh4(f32x4 z) {
    f32x4 r;
    r[0] = fast_tanh(z[0]); r[1] = fast_tanh(z[1]);
    r[2] = fast_tanh(z[2]); r[3] = fast_tanh(z[3]);
    return r;
}

__device__ __forceinline__ unsigned short bf16_bits(float v) {
    __hip_bfloat16 b = __float2bfloat16(v);
    unsigned short s; __builtin_memcpy(&s, &b, 2);
    return s;
}
// HW packed convert (R26: -11%; compiler does NOT pattern-match this).
__device__ __forceinline__ unsigned pack_bf2(float lo, float hi) {
    unsigned r;
    asm("v_cvt_pk_bf16_f32 %0, %1, %2" : "=v"(r) : "v"(lo), "v"(hi));
    return r;
}
__device__ __forceinline__ short8 packB(f32x4 lo, f32x4 hi) {
    uint4v u;
    u[0] = pack_bf2(lo[0], lo[1]);
    u[1] = pack_bf2(lo[2], lo[3]);
    u[2] = pack_bf2(hi[0], hi[1]);
    u[3] = pack_bf2(hi[2], hi[3]);
    return __builtin_bit_cast(short8, u);
}
__device__ __forceinline__ f32x4 mfma(short8 a, short8 b, f32x4 c) {
    return __builtin_amdgcn_mfma_f32_16x16x32_bf16(a, b, c, 0, 0, 0);
}

__device__ __forceinline__ Acc8 acc_zero() {
    Acc8 A;
    A.n0 = sp4(0.f); A.n1 = sp4(0.f); A.n2 = sp4(0.f); A.n3 = sp4(0.f);
    A.n4 = sp4(0.f); A.n5 = sp4(0.f); A.n6 = sp4(0.f); A.n7 = sp4(0.f);
    return A;
}
__device__ __forceinline__ Acc8 acc_bias(const float* bp, int fb) {
    Acc8 A;
    A.n0 = *(const f32x4*)(bp + 0 * 16 + fb);
    A.n1 = *(const f32x4*)(bp + 1 * 16 + fb);
    A.n2 = *(const f32x4*)(bp + 2 * 16 + fb);
    A.n3 = *(const f32x4*)(bp + 3 * 16 + fb);
    A.n4 = *(const f32x4*)(bp + 4 * 16 + fb);
    A.n5 = *(const f32x4*)(bp + 5 * 16 + fb);
    A.n6 = *(const f32x4*)(bp + 6 * 16 + fb);
    A.n7 = *(const f32x4*)(bp + 7 * 16 + fb);
    return A;
}

__device__ __forceinline__ float red16(float v) {
    v += __shfl_xor(v, 16, 64);
    v += __shfl_xor(v, 32, 64);
    return v;
}
__device__ __forceinline__ float hsum4(f32x4 v) {
    return (v[0] + v[1]) + (v[2] + v[3]);
}

__global__ __launch_bounds__(TPB, 1) __attribute__((amdgpu_waves_per_eu(1)))
void mlp_jet_kernel(
    const float* __restrict__ X,
    const float* __restrict__ gW1, const float* __restrict__ gB1,
    const float* __restrict__ gW2, const float* __restrict__ gB2,
    const float* __restrict__ gW3, const float* __restrict__ gB3,
    const float* __restrict__ gW4, const float* __restrict__ gB4,
    float* __restrict__ out, int N)
{
    __shared__ alignas(16) unsigned short sPanel[2 * PSZ];           // 69632 B
    __shared__ alignas(16) float sParam[7 * 128];                    // 3584 B -> 73216 total

    const int tid = threadIdx.x;
    for (int idx = tid; idx < 2 * 128 * 128; idx += TPB) {
        int p = idx >> 14, e = idx & 16383, n = e >> 7, pp = e & 127;
        int kk = pp >> 5, gg = (pp >> 3) & 3, jj = pp & 7;
        int f = ((((jj >> 2) << 2) | kk) << 4) | (gg << 2) | (jj & 3);  // invsigma
        const float* Wsrc = p ? gW3 : gW2;
        sPanel[p * PSZ + n * PROW + pp] = bf16_bits(Wsrc[f * 128 + n]);
    }
    if (tid < 128) {
        sParam[0 * 128 + tid] = gW1[tid];
        sParam[1 * 128 + tid] = gW1[128 + tid];
        sParam[2 * 128 + tid] = gW1[256 + tid];
        sParam[3 * 128 + tid] = gB1[tid];
        sParam[4 * 128 + tid] = gB2[tid];
        sParam[5 * 128 + tid] = gB3[tid];
        sParam[6 * 128 + tid] = gW4[tid];
    }
    __syncthreads();

    const int lane = tid & 63;
    const int wave = tid >> 6;
    const int c = lane & 15, g = lane >> 4;
    const int fb = g << 2;
    const unsigned short* const pW2f = sPanel;
    const unsigned short* const pW3f = sPanel + PSZ;
    const float b4 = gB4[0];
    const float* const w4p = sParam + 6 * 128;

    const int tiles = N >> 4;
    for (int t = blockIdx.x * WPB + wave; t < tiles; t += NBLK * WPB) {
        const int sbase = t << 4;
        const float* xp = X + (long)(sbase + c) * 3;
        const float xt = xp[0], xx = xp[1], xy = xp[2];

        // ---- FUSED layer-1 seeds (no barriers) ----
        Frag h1F, t1t, t1x, t1y, s1x, s1y;
#define SEED(K, IL, IH) { \
    const int fL = (IL) * 16 + fb, fH = (IH) * 16 + fb; \
    f32x4 wtL = *(const f32x4*)(sParam + fL),        wtH = *(const f32x4*)(sParam + fH); \
    f32x4 wxL = *(const f32x4*)(sParam + 128 + fL),  wxH = *(const f32x4*)(sParam + 128 + fH); \
    f32x4 wyL = *(const f32x4*)(sParam + 256 + fL),  wyH = *(const f32x4*)(sParam + 256 + fH); \
    f32x4 bbL = *(const f32x4*)(sParam + 384 + fL),  bbH = *(const f32x4*)(sParam + 384 + fH); \
    f32x4 hL = tanh4(sp4(xt) * wtL + sp4(xx) * wxL + sp4(xy) * wyL + bbL); \
    f32x4 hH = tanh4(sp4(xt) * wtH + sp4(xx) * wxH + sp4(xy) * wyH + bbH); \
    f32x4 aL = sp4(1.f) - hL * hL, aH = sp4(1.f) - hH * hH; \
    h1F.K = packB(hL, hH); \
    t1t.K = packB(aL * wtL, aH * wtH); \
    t1x.K = packB(aL * wxL, aH * wxH); \
    t1y.K = packB(aL * wyL, aH * wyH); \
    s1x.K = packB((sp4(0.f) - hL) * aL * wxL * wxL, (sp4(0.f) - hH) * aH * wxH * wxH); \
    s1y.K = packB((sp4(0.f) - hL) * aL * wyL * wyL, (sp4(0.f) - hH) * aH * wyH * wyH); }
        SEED(k0, 0, 4) SEED(k1, 1, 5) SEED(k2, 2, 6) SEED(k3, 3, 7)
#undef SEED

        // ================= layer 2 (phase-interleaved) =================
        // MROW: A-frag read + 6 MFMAs into acc row N with B element k{KK}.
        // MPHASE completes acc pair (NTa=N_a, NTb=N_b) over full K (order
        // k0->k3 per acc = identical accumulation order to R27 -> bit-identical).
        // POST2 slice for pair I sits in the SAME barrier region as phase I+1's
        // MFMAs: independent -> scheduler interleaves VALU under the MFMA pipe.
        Acc8x6 R6;
        R6.a = acc_bias(sParam + 4 * 128, fb);
        R6.b = acc_zero(); R6.c = acc_zero(); R6.d = acc_zero();
        R6.e = acc_zero(); R6.f = acc_zero();
#define MROW(PNL, NT, N, KK, F0, F1, F2, F3, F4, F5) { \
    const short8 af = *reinterpret_cast<const short8*>( \
        PNL + ((NT) * 16 + c) * PROW + (KK) * 32 + g * 8); \
    R6.a.N = mfma(af, F0.k##KK, R6.a.N); \
    R6.b.N = mfma(af, F1.k##KK, R6.b.N); \
    R6.c.N = mfma(af, F2.k##KK, R6.c.N); \
    R6.d.N = mfma(af, F3.k##KK, R6.d.N); \
    R6.e.N = mfma(af, F4.k##KK, R6.e.N); \
    R6.f.N = mfma(af, F5.k##KK, R6.f.N); }
#define MPHASE(PNL, NTa, Na, NTb, Nb, F0, F1, F2, F3, F4, F5) \
    MROW(PNL, NTa, Na, 0, F0,F1,F2,F3,F4,F5) MROW(PNL, NTa, Na, 1, F0,F1,F2,F3,F4,F5) \
    MROW(PNL, NTa, Na, 2, F0,F1,F2,F3,F4,F5) MROW(PNL, NTa, Na, 3, F0,F1,F2,F3,F4,F5) \
    MROW(PNL, NTb, Nb, 0, F0,F1,F2,F3,F4,F5) MROW(PNL, NTb, Nb, 1, F0,F1,F2,F3,F4,F5) \
    MROW(PNL, NTb, Nb, 2, F0,F1,F2,F3,F4,F5) MROW(PNL, NTb, Nb, 3, F0,F1,F2,F3,F4,F5)

        Frag h2F, t2t, txF, tyF, s2xF, s2yF;
#define POST2(K, NL, NH) { \
    f32x4 hL = tanh4(R6.a.NL), hH = tanh4(R6.a.NH); \
    f32x4 aL = sp4(1.f) - hL * hL, aH = sp4(1.f) - hH * hH; \
    h2F.K = packB(hL, hH); \
    t2t.K = packB(aL * R6.b.NL, aH * R6.b.NH); \
    f32x4 txL = aL * R6.c.NL, txH = aH * R6.c.NH; \
    txF.K = packB(txL, txH); \
    f32x4 pxL = (sp4(0.f) - hL) * txL * R6.c.NL, pxH = (sp4(0.f) - hH) * txH * R6.c.NH; \
    f32x4 tyL = aL * R6.d.NL, tyH = aH * R6.d.NH; \
    tyF.K = packB(tyL, tyH); \
    f32x4 pyL = (sp4(0.f) - hL) * tyL * R6.d.NL, pyH = (sp4(0.f) - hH) * tyH * R6.d.NH; \
    s2xF.K = packB(aL * R6.e.NL + pxL, aH * R6.e.NH + pxH); \
    s2yF.K = packB(aL * R6.f.NL + pyL, aH * R6.f.NH + pyH); }

        MPHASE(pW2f, 0, n0, 4, n4, h1F, t1t, t1x, t1y, s1x, s1y)
        SBAR();
        POST2(k0, n0, n4)
        MPHASE(pW2f, 1, n1, 5, n5, h1F, t1t, t1x, t1y, s1x, s1y)
        SBAR();
        POST2(k1, n1, n5)
        MPHASE(pW2f, 2, n2, 6, n6, h1F, t1t, t1x, t1y, s1x, s1y)
        SBAR();
        POST2(k2, n2, n6)
        MPHASE(pW2f, 3, n3, 7, n7, h1F, t1t, t1x, t1y, s1x, s1y)
        SBAR();
        POST2(k3, n3, n7)
#undef POST2

        // ================= layer 3 (phase-interleaved with DOTS) =================
        R6.a = acc_bias(sParam + 5 * 128, fb);
        R6.b = acc_zero(); R6.c = acc_zero(); R6.d = acc_zero();
        R6.e = acc_zero(); R6.f = acc_zero();

        f32x4 scp = sp4(0.f), sc1t = sp4(0.f);
        f32x4 srxa = sp4(0.f), srxb = sp4(0.f);
        f32x4 srya = sp4(0.f), sryb = sp4(0.f);
        f32x4 sc2x = sp4(0.f), sc2y = sp4(0.f);
#define DOTS(NL, NH, IL, IH) { \
    f32x4 w4L = *(const f32x4*)(w4p + (IL) * 16 + fb); \
    f32x4 w4H = *(const f32x4*)(w4p + (IH) * 16 + fb); \
    f32x4 hL = tanh4(R6.a.NL), hH = tanh4(R6.a.NH); \
    f32x4 waL = w4L * (sp4(1.f) - hL * hL), waH = w4H * (sp4(1.f) - hH * hH); \
    scp  += w4L * hL + w4H * hH; \
    sc1t += waL * R6.b.NL + waH * R6.b.NH; \
    f32x4 wtxL = waL * R6.c.NL, wtxH = waH * R6.c.NH; \
    srxa += wtxL + wtxH; \
    srxb -= wtxL * hL * R6.c.NL + wtxH * hH * R6.c.NH; \
    f32x4 wtyL = waL * R6.d.NL, wtyH = waH * R6.d.NH; \
    srya += wtyL + wtyH; \
    sryb -= wtyL * hL * R6.d.NL + wtyH * hH * R6.d.NH; \
    sc2x += waL * R6.e.NL + waH * R6.e.NH; \
    sc2y += waL * R6.f.NL + waH * R6.f.NH; }

        MPHASE(pW3f, 0, n0, 4, n4, h2F, t2t, txF, tyF, s2xF, s2yF)
        SBAR();
        DOTS(n0, n4, 0, 4)
        MPHASE(pW3f, 1, n1, 5, n5, h2F, t2t, txF, tyF, s2xF, s2yF)
        SBAR();
        DOTS(n1, n5, 1, 5)
        MPHASE(pW3f, 2, n2, 6, n6, h2F, t2t, txF, tyF, s2xF, s2yF)
        SBAR();
        DOTS(n2, n6, 2, 6)
        MPHASE(pW3f, 3, n3, 7, n7, h2F, t2t, txF, tyF, s2xF, s2yF)
        SBAR();
        DOTS(n3, n7, 3, 7)
#undef DOTS
#undef MPHASE
#undef MROW

        {
            float cp  = red16(hsum4(scp));
            float c1t = red16(hsum4(sc1t));
            float c1x = red16(hsum4(srxa));
            float c1y = red16(hsum4(srya));
            float c2x = red16(hsum4(srxb) + hsum4(sc2x));
            float c2y = red16(hsum4(sryb) + hsum4(sc2y));
            if (lane < 16) {
                out[sbase + lane]           = cp + b4;
                out[(long)N + sbase + lane] = c1t;
                out[2L * N + sbase + lane]  = c1x;
                out[3L * N + sbase + lane]  = c1y;
                out[4L * N + sbase + lane]  = 2.f * c2x;
                out[5L * N + sbase + lane]  = 2.f * c2y;
            }
        }
    }
}

extern "C" void kernel_launch(void* const* d_in, const int* in_sizes, int n_in,
                              void* d_out, int out_size, void* d_ws, size_t ws_size,
                              hipStream_t stream) {
    const float* X  = (const float*)d_in[0];
    const float* W1 = (const float*)d_in[1];
    const float* B1 = (const float*)d_in[2];
    const float* W2 = (const float*)d_in[3];
    const float* B2 = (const float*)d_in[4];
    const float* W3 = (const float*)d_in[5];
    const float* B3 = (const float*)d_in[6];
    const float* W4 = (const float*)d_in[7];
    const float* B4 = (const float*)d_in[8];
    float* out = (float*)d_out;
    const int N = in_sizes[0] / 3;

    mlp_jet_kernel<<<NBLK, TPB, 0, stream>>>(X, W1, B1, W2, B2, W3, B3, W4, B4, out, N);
}